// Round 2
// baseline (224.908 us; speedup 1.0000x reference)
//
#include <hip/hip_runtime.h>
#include <cstdint>
#include <cstddef>

// Problem constants (fixed by reference setup_inputs)
#define DIMD 1024
#define BB 2
#define NN 4096
#define MM (BB*NN)      // 8192 rows
#define EE (3*DIMD)     // 3072 output cols
#define KK DIMD         // 1024

typedef __attribute__((ext_vector_type(8))) short short8;
typedef __attribute__((ext_vector_type(4))) float f32x4;

__device__ __forceinline__ unsigned short f2bf(float f) {
  unsigned int u = __float_as_uint(f);
  u += 0x7FFF + ((u >> 16) & 1);          // round-to-nearest-even
  return (unsigned short)(u >> 16);
}

// ---------------- cast W (3072x1024 f32) -> bf16 ----------------
__global__ void cast_w_kernel(const float* __restrict__ w, unsigned short* __restrict__ wb) {
  int i = blockIdx.x * blockDim.x + threadIdx.x;  // one float4 each
  const float4* w4 = (const float4*)w;
  float4 v = w4[i];
  unsigned int lo = (unsigned int)f2bf(v.x) | ((unsigned int)f2bf(v.y) << 16);
  unsigned int hi = (unsigned int)f2bf(v.z) | ((unsigned int)f2bf(v.w) << 16);
  ((uint2*)wb)[i] = make_uint2(lo, hi);
}

// ---------------- RMSNorm + cast to bf16 ----------------
// out xn[row][d] = x/max(||x||,eps) * sqrt(D) * gamma, one block (256 thr) per row
__global__ void rmsnorm_kernel(const float* __restrict__ x, const float* __restrict__ gamma,
                               unsigned short* __restrict__ xn) {
  int row = blockIdx.x;
  int tid = threadIdx.x;
  const float4* x4 = (const float4*)(x + (size_t)row * DIMD);
  float4 v = x4[tid];
  float ss = v.x*v.x + v.y*v.y + v.z*v.z + v.w*v.w;
  #pragma unroll
  for (int m = 32; m >= 1; m >>= 1) ss += __shfl_xor(ss, m);
  __shared__ float red[4];
  if ((tid & 63) == 0) red[tid >> 6] = ss;
  __syncthreads();
  float tot = red[0] + red[1] + red[2] + red[3];
  float scale = 32.0f / fmaxf(sqrtf(tot), 1e-12f);   // sqrt(1024)=32
  const float4* g4 = (const float4*)gamma;
  float4 g = g4[tid];
  float a0 = v.x*scale*g.x, a1 = v.y*scale*g.y, a2 = v.z*scale*g.z, a3 = v.w*scale*g.w;
  unsigned int lo = (unsigned int)f2bf(a0) | ((unsigned int)f2bf(a1) << 16);
  unsigned int hi = (unsigned int)f2bf(a2) | ((unsigned int)f2bf(a3) << 16);
  ((uint2*)(xn + (size_t)row * DIMD))[tid] = make_uint2(lo, hi);
}

// ---------------- GEMM: C[M][E] = Xn[M][K] * W[E][K]^T, bf16 MFMA ----------------
// 128x128 tile, BK=64, 4 waves (2x2), each wave 64x64 = 4x4 fragments of 16x16x32.
// LDS tiles XOR-swizzled (T2): chunk c' = c ^ (row&7) so ds_read_b128 is conflict-free.
// Epilogue applies sigmoid to cols >= 2048 (the "a" third).
#define BM 128
#define BN 128
#define BK 64

__global__ __launch_bounds__(256) void gemm_kernel(const unsigned short* __restrict__ A,
                                                   const unsigned short* __restrict__ Bw,
                                                   float* __restrict__ C) {
  __shared__ unsigned short Al[BM][BK];   // 16 KiB
  __shared__ unsigned short Bl[BN][BK];   // 16 KiB
  int tid = threadIdx.x;
  int l = tid & 63;
  int w = tid >> 6;
  int wr = w >> 1, wc = w & 1;
  int m0 = blockIdx.y * BM;
  int n0 = blockIdx.x * BN;
  int lrow = l & 15, lk = l >> 4;

  f32x4 acc[4][4];
  #pragma unroll
  for (int i = 0; i < 4; i++)
    #pragma unroll
    for (int j = 0; j < 4; j++) acc[i][j] = (f32x4)(0.f);

  for (int k0 = 0; k0 < KK; k0 += BK) {
    short8 ar[4], br[4];
    #pragma unroll
    for (int j = 0; j < 4; j++) {
      int cid = j*256 + tid;
      int row = cid >> 3, cb = cid & 7;   // 8 chunks of 16B per 128B row
      ar[j] = *(const short8*)(A  + (size_t)(m0 + row)*KK + k0 + cb*8);
      br[j] = *(const short8*)(Bw + (size_t)(n0 + row)*KK + k0 + cb*8);
    }
    __syncthreads();   // previous iter's LDS reads done
    #pragma unroll
    for (int j = 0; j < 4; j++) {
      int cid = j*256 + tid;
      int row = cid >> 3, cb = cid & 7;
      *(short8*)&Al[row][(cb ^ (row & 7)) * 8] = ar[j];
      *(short8*)&Bl[row][(cb ^ (row & 7)) * 8] = br[j];
    }
    __syncthreads();
    #pragma unroll
    for (int s = 0; s < 2; s++) {
      short8 af[4], bf[4];
      #pragma unroll
      for (int i = 0; i < 4; i++) {
        int r = wr*64 + i*16 + lrow;
        af[i] = *(const short8*)&Al[r][((s*4 + lk) ^ (r & 7)) * 8];
      }
      #pragma unroll
      for (int j = 0; j < 4; j++) {
        int r = wc*64 + j*16 + lrow;
        bf[j] = *(const short8*)&Bl[r][((s*4 + lk) ^ (r & 7)) * 8];
      }
      #pragma unroll
      for (int i = 0; i < 4; i++)
        #pragma unroll
        for (int j = 0; j < 4; j++)
          acc[i][j] = __builtin_amdgcn_mfma_f32_16x16x32_bf16(af[i], bf[j], acc[i][j], 0, 0, 0);
    }
  }

  // epilogue: C/D layout col = lane&15, row = (lane>>4)*4 + r  [m89-verified]
  #pragma unroll
  for (int i = 0; i < 4; i++) {
    int rowb = m0 + wr*64 + i*16 + lk*4;
    #pragma unroll
    for (int j = 0; j < 4; j++) {
      int col = n0 + wc*64 + j*16 + lrow;
      f32x4 v = acc[i][j];
      bool isg = (col >= 2*DIMD);
      #pragma unroll
      for (int r = 0; r < 4; r++) {
        float val = v[r];
        if (isg) val = 1.0f / (1.0f + __expf(-val));
        C[(size_t)(rowb + r)*EE + col] = val;
      }
    }
  }
}

// ---------------- chunked scan over n ----------------
#define CHUNK 128
#define NCH (NN / CHUNK)   // 32

// pass 1: per-chunk aggregates (A = prod a, KV = chunk-local scan end value)
__global__ void scan1_kernel(const float* __restrict__ qkva,
                             float* __restrict__ Aagg, float* __restrict__ Kagg) {
  int d = blockIdx.x * 256 + threadIdx.x;
  int c = blockIdx.y;
  int b = blockIdx.z;
  const float* p = qkva + ((size_t)(b*NN + c*CHUNK)) * EE;
  float Aa = 1.f, Kv = 0.f;
  for (int i = 0; i < CHUNK; i++) {
    float a  = p[2*DIMD + d];
    float kv = p[DIMD + d];
    Kv = fmaf(a, Kv, kv);
    Aa *= a;
    p += EE;
  }
  int idx = (b*NCH + c)*DIMD + d;
  Aagg[idx] = Aa;
  Kagg[idx] = Kv;
}

// pass 2: exclusive prefix over chunks (per b,d channel; 2048 threads)
__global__ void scan2_kernel(const float* __restrict__ Aagg, const float* __restrict__ Kagg,
                             float* __restrict__ carry) {
  int t = blockIdx.x * 256 + threadIdx.x;   // 0..2047
  int b = t >> 10, d = t & (DIMD - 1);
  float cy = 0.f;
  for (int c = 0; c < NCH; c++) {
    int idx = (b*NCH + c)*DIMD + d;
    carry[idx] = cy;
    cy = fmaf(Aagg[idx], cy, Kagg[idx]);
  }
}

// pass 3: re-scan each chunk with its carry, write out = q * kv_scan
__global__ void scan3_kernel(const float* __restrict__ qkva, const float* __restrict__ carry,
                             float* __restrict__ out) {
  int d = blockIdx.x * 256 + threadIdx.x;
  int c = blockIdx.y;
  int b = blockIdx.z;
  const float* p = qkva + ((size_t)(b*NN + c*CHUNK)) * EE;
  float* o = out + ((size_t)(b*NN + c*CHUNK)) * DIMD;
  float Kv = carry[(b*NCH + c)*DIMD + d];
  for (int i = 0; i < CHUNK; i++) {
    float a  = p[2*DIMD + d];
    float kv = p[DIMD + d];
    float q  = p[d];
    Kv = fmaf(a, Kv, kv);
    o[d] = q * Kv;
    p += EE;
    o += DIMD;
  }
}

// ---------------- launch ----------------
// ws layout (bytes):
//   [0, 6 MiB)            W bf16        3072*1024*2
//   [6 MiB, 22 MiB)       Xn bf16       8192*1024*2
//   [22 MiB, 118 MiB)     qkva f32      8192*3072*4
//   then Aagg / Kagg / carry, 256 KiB each.  Total ~119 MiB.
extern "C" void kernel_launch(void* const* d_in, const int* in_sizes, int n_in,
                              void* d_out, int out_size, void* d_ws, size_t ws_size,
                              hipStream_t stream) {
  const float* x     = (const float*)d_in[0];
  const float* gamma = (const float*)d_in[1];
  const float* wq    = (const float*)d_in[2];
  float* out = (float*)d_out;
  char* ws = (char*)d_ws;

  unsigned short* Wb = (unsigned short*)ws;                       // 6,291,456 B
  unsigned short* Xn = (unsigned short*)(ws + 6291456);           // 16,777,216 B
  float* qkva        = (float*)(ws + 23068672);                   // 100,663,296 B
  float* Aagg        = (float*)(ws + 123731968);                  // 262,144 B
  float* Kagg        = (float*)(ws + 123994112);                  // 262,144 B
  float* carry       = (float*)(ws + 124256256);                  // 262,144 B

  cast_w_kernel<<<(EE*KK)/(256*4), 256, 0, stream>>>(wq, Wb);
  rmsnorm_kernel<<<MM, 256, 0, stream>>>(x, gamma, Xn);
  gemm_kernel<<<dim3(EE/BN, MM/BM), 256, 0, stream>>>(Xn, Wb, qkva);
  scan1_kernel<<<dim3(DIMD/256, NCH, BB), 256, 0, stream>>>(qkva, Aagg, Kagg);
  scan2_kernel<<<dim3((BB*DIMD)/256), 256, 0, stream>>>(Aagg, Kagg, carry);
  scan3_kernel<<<dim3(DIMD/256, NCH, BB), 256, 0, stream>>>(qkva, carry, out);
}

// Round 4
// 209.433 us; speedup vs baseline: 1.0739x; 1.0739x over previous
//
#include <hip/hip_runtime.h>
#include <cstdint>
#include <cstddef>

// Problem constants (fixed by reference setup_inputs)
#define DIMD 1024
#define BB 2
#define NN 4096
#define MM (BB*NN)      // 8192 rows
#define EE (3*DIMD)     // 3072 output cols
#define KK DIMD         // 1024

typedef __attribute__((ext_vector_type(8))) short short8;
typedef __attribute__((ext_vector_type(4))) float f32x4;

__device__ __forceinline__ unsigned short f2bf(float f) {
  unsigned int u = __float_as_uint(f);
  u += 0x7FFF + ((u >> 16) & 1);          // round-to-nearest-even
  return (unsigned short)(u >> 16);
}

// async global->LDS, 16B per lane, wave-uniform LDS base + lane*16 (m97 recipe)
#define GLOAD_LDS16(gptr, lptr) \
  __builtin_amdgcn_global_load_lds((const __attribute__((address_space(1))) void*)(gptr), \
                                   (__attribute__((address_space(3))) void*)(lptr), 16, 0, 0)

// ---------------- cast W (3072x1024 f32) -> bf16 ----------------
__global__ void cast_w_kernel(const float* __restrict__ w, unsigned short* __restrict__ wb) {
  int i = blockIdx.x * blockDim.x + threadIdx.x;  // one float4 each
  const float4* w4 = (const float4*)w;
  float4 v = w4[i];
  unsigned int lo = (unsigned int)f2bf(v.x) | ((unsigned int)f2bf(v.y) << 16);
  unsigned int hi = (unsigned int)f2bf(v.z) | ((unsigned int)f2bf(v.w) << 16);
  ((uint2*)wb)[i] = make_uint2(lo, hi);
}

// ---------------- RMSNorm + cast to bf16 ----------------
__global__ void rmsnorm_kernel(const float* __restrict__ x, const float* __restrict__ gamma,
                               unsigned short* __restrict__ xn) {
  int row = blockIdx.x;
  int tid = threadIdx.x;
  const float4* x4 = (const float4*)(x + (size_t)row * DIMD);
  float4 v = x4[tid];
  float ss = v.x*v.x + v.y*v.y + v.z*v.z + v.w*v.w;
  #pragma unroll
  for (int m = 32; m >= 1; m >>= 1) ss += __shfl_xor(ss, m);
  __shared__ float red[4];
  if ((tid & 63) == 0) red[tid >> 6] = ss;
  __syncthreads();
  float tot = red[0] + red[1] + red[2] + red[3];
  float scale = 32.0f / fmaxf(sqrtf(tot), 1e-12f);   // sqrt(1024)=32
  const float4* g4 = (const float4*)gamma;
  float4 g = g4[tid];
  float a0 = v.x*scale*g.x, a1 = v.y*scale*g.y, a2 = v.z*scale*g.z, a3 = v.w*scale*g.w;
  unsigned int lo = (unsigned int)f2bf(a0) | ((unsigned int)f2bf(a1) << 16);
  unsigned int hi = (unsigned int)f2bf(a2) | ((unsigned int)f2bf(a3) << 16);
  ((uint2*)(xn + (size_t)row * DIMD))[tid] = make_uint2(lo, hi);
}

// ---------------- GEMM: C[M][E] = Xn[M][K] * W[E][K]^T, bf16 MFMA ----------------
// 128x128 tile, BK=64, 4 waves (2x2), each wave 64x64 = 4x4 fragments of 16x16x32.
// Staging via global_load_lds (linear LDS dest). Rule #21: swizzle realized by
// inverse-permuting the per-lane GLOBAL source chunk; LDS slot c' holds global
// chunk c'^(row&7), ds_read applies the same XOR. Content bitwise identical to
// the round-2 reg-staged version.
#define BM 128
#define BN 128
#define BK 64

__global__ __launch_bounds__(256) void gemm_kernel(const unsigned short* __restrict__ A,
                                                   const unsigned short* __restrict__ Bw,
                                                   float* __restrict__ C) {
  __shared__ unsigned short Al[BM][BK];   // 16 KiB
  __shared__ unsigned short Bl[BN][BK];   // 16 KiB
  int tid = threadIdx.x;
  int l = tid & 63;
  int w = tid >> 6;
  int wr = w >> 1, wc = w & 1;
  int m0 = blockIdx.y * BM;
  int n0 = blockIdx.x * BN;
  int lrow = l & 15, lk = l >> 4;

  // staging geometry: wave w covers rows [w*32, w*32+32); per instruction t,
  // lane l writes LDS row w*32+t*8+(l>>3), 16B chunk (l&7).  row&7 == l>>3.
  int srow_base = w * 32 + (l >> 3);
  int scol = (((l & 7) ^ (l >> 3)) * 8);   // inverse-swizzled source chunk (elements)

  f32x4 acc[4][4];
  #pragma unroll
  for (int i = 0; i < 4; i++)
    #pragma unroll
    for (int j = 0; j < 4; j++) acc[i][j] = (f32x4)(0.f);

  for (int k0 = 0; k0 < KK; k0 += BK) {
    __syncthreads();   // previous iter's LDS reads done before overwrite
    #pragma unroll
    for (int t = 0; t < 4; t++) {
      int row = srow_base + t * 8;
      GLOAD_LDS16(A  + (size_t)(m0 + row) * KK + k0 + scol, &Al[w*32 + t*8][0]);
      GLOAD_LDS16(Bw + (size_t)(n0 + row) * KK + k0 + scol, &Bl[w*32 + t*8][0]);
    }
    __syncthreads();   // drains vmcnt(0): tiles resident
    #pragma unroll
    for (int s = 0; s < 2; s++) {
      short8 af[4], bf[4];
      #pragma unroll
      for (int i = 0; i < 4; i++) {
        int r = wr*64 + i*16 + lrow;
        af[i] = *(const short8*)&Al[r][((s*4 + lk) ^ (r & 7)) * 8];
      }
      #pragma unroll
      for (int j = 0; j < 4; j++) {
        int r = wc*64 + j*16 + lrow;
        bf[j] = *(const short8*)&Bl[r][((s*4 + lk) ^ (r & 7)) * 8];
      }
      #pragma unroll
      for (int i = 0; i < 4; i++)
        #pragma unroll
        for (int j = 0; j < 4; j++)
          acc[i][j] = __builtin_amdgcn_mfma_f32_16x16x32_bf16(af[i], bf[j], acc[i][j], 0, 0, 0);
    }
  }

  // epilogue: C/D layout col = lane&15, row = (lane>>4)*4 + r  [m89-verified]
  #pragma unroll
  for (int i = 0; i < 4; i++) {
    int rowb = m0 + wr*64 + i*16 + lk*4;
    #pragma unroll
    for (int j = 0; j < 4; j++) {
      int col = n0 + wc*64 + j*16 + lrow;
      f32x4 v = acc[i][j];
      bool isg = (col >= 2*DIMD);
      #pragma unroll
      for (int r = 0; r < 4; r++) {
        float val = v[r];
        if (isg) val = 1.0f / (1.0f + __expf(-val));
        C[(size_t)(rowb + r)*EE + col] = val;
      }
    }
  }
}

// ---------------- chunked scan over n ----------------
// Latency fix: batch 8 iterations' loads before the fmaf chain so ~16-24
// loads are outstanding per wave (round 2 was 1 latency per iteration).
#define CHUNK 128
#define NCH (NN / CHUNK)   // 32

// pass 1: per-chunk aggregates (A = prod a, KV = chunk-local scan end value)
__global__ void scan1_kernel(const float* __restrict__ qkva,
                             float* __restrict__ Aagg, float* __restrict__ Kagg) {
  int d = blockIdx.x * 256 + threadIdx.x;
  int c = blockIdx.y;
  int b = blockIdx.z;
  const float* p = qkva + ((size_t)(b*NN + c*CHUNK)) * EE;
  float Aa = 1.f, Kv = 0.f;
  for (int i0 = 0; i0 < CHUNK; i0 += 8) {
    float av[8], kvv[8];
    #pragma unroll
    for (int u = 0; u < 8; u++) av[u]  = p[(size_t)(i0+u)*EE + 2*DIMD + d];
    #pragma unroll
    for (int u = 0; u < 8; u++) kvv[u] = p[(size_t)(i0+u)*EE + DIMD + d];
    #pragma unroll
    for (int u = 0; u < 8; u++) { Kv = fmaf(av[u], Kv, kvv[u]); Aa *= av[u]; }
  }
  int idx = (b*NCH + c)*DIMD + d;
  Aagg[idx] = Aa;
  Kagg[idx] = Kv;
}

// pass 2: exclusive prefix over chunks (per b,d channel; 2048 threads)
__global__ void scan2_kernel(const float* __restrict__ Aagg, const float* __restrict__ Kagg,
                             float* __restrict__ carry) {
  int t = blockIdx.x * 256 + threadIdx.x;   // 0..2047
  int b = t >> 10, d = t & (DIMD - 1);
  float cy = 0.f;
  for (int c0 = 0; c0 < NCH; c0 += 8) {
    float Av[8], Kv[8];
    #pragma unroll
    for (int u = 0; u < 8; u++) {
      int idx = (b*NCH + c0 + u)*DIMD + d;
      Av[u] = Aagg[idx]; Kv[u] = Kagg[idx];
    }
    #pragma unroll
    for (int u = 0; u < 8; u++) {
      carry[(b*NCH + c0 + u)*DIMD + d] = cy;
      cy = fmaf(Av[u], cy, Kv[u]);
    }
  }
}

// pass 3: re-scan each chunk with its carry, write out = q * kv_scan
__global__ void scan3_kernel(const float* __restrict__ qkva, const float* __restrict__ carry,
                             float* __restrict__ out) {
  int d = blockIdx.x * 256 + threadIdx.x;
  int c = blockIdx.y;
  int b = blockIdx.z;
  const float* p = qkva + ((size_t)(b*NN + c*CHUNK)) * EE;
  float* o = out + ((size_t)(b*NN + c*CHUNK)) * DIMD;
  float Kv = carry[(b*NCH + c)*DIMD + d];
  for (int i0 = 0; i0 < CHUNK; i0 += 8) {
    float av[8], kvv[8], qv[8];
    #pragma unroll
    for (int u = 0; u < 8; u++) av[u]  = p[(size_t)(i0+u)*EE + 2*DIMD + d];
    #pragma unroll
    for (int u = 0; u < 8; u++) kvv[u] = p[(size_t)(i0+u)*EE + DIMD + d];
    #pragma unroll
    for (int u = 0; u < 8; u++) qv[u]  = p[(size_t)(i0+u)*EE + d];
    #pragma unroll
    for (int u = 0; u < 8; u++) {
      Kv = fmaf(av[u], Kv, kvv[u]);
      o[(size_t)(i0+u)*DIMD + d] = qv[u] * Kv;
    }
  }
}

// ---------------- launch ----------------
// ws layout (bytes):
//   [0, 6 MiB)            W bf16        3072*1024*2
//   [6 MiB, 22 MiB)       Xn bf16       8192*1024*2
//   [22 MiB, 118 MiB)     qkva f32      8192*3072*4
//   then Aagg / Kagg / carry, 256 KiB each.  Total ~119 MiB (same as round 2).
extern "C" void kernel_launch(void* const* d_in, const int* in_sizes, int n_in,
                              void* d_out, int out_size, void* d_ws, size_t ws_size,
                              hipStream_t stream) {
  const float* x     = (const float*)d_in[0];
  const float* gamma = (const float*)d_in[1];
  const float* wq    = (const float*)d_in[2];
  float* out = (float*)d_out;
  char* ws = (char*)d_ws;

  unsigned short* Wb = (unsigned short*)ws;                       // 6,291,456 B
  unsigned short* Xn = (unsigned short*)(ws + 6291456);           // 16,777,216 B
  float* qkva        = (float*)(ws + 23068672);                   // 100,663,296 B
  float* Aagg        = (float*)(ws + 123731968);                  // 262,144 B
  float* Kagg        = (float*)(ws + 123994112);                  // 262,144 B
  float* carry       = (float*)(ws + 124256256);                  // 262,144 B

  cast_w_kernel<<<(EE*KK)/(256*4), 256, 0, stream>>>(wq, Wb);
  rmsnorm_kernel<<<MM, 256, 0, stream>>>(x, gamma, Xn);
  gemm_kernel<<<dim3(EE/BN, MM/BM), 256, 0, stream>>>(Xn, Wb, qkva);
  scan1_kernel<<<dim3(DIMD/256, NCH, BB), 256, 0, stream>>>(qkva, Aagg, Kagg);
  scan2_kernel<<<dim3((BB*DIMD)/256), 256, 0, stream>>>(Aagg, Kagg, carry);
  scan3_kernel<<<dim3(DIMD/256, NCH, BB), 256, 0, stream>>>(qkva, carry, out);
}

// Round 7
// 204.424 us; speedup vs baseline: 1.1002x; 1.0245x over previous
//
#include <hip/hip_runtime.h>
#include <cstdint>
#include <cstddef>

// Problem constants (fixed by reference setup_inputs)
#define DIMD 1024
#define BB 2
#define NN 4096
#define MM (BB*NN)      // 8192 rows
#define EE (3*DIMD)     // 3072 output cols
#define KK DIMD         // 1024

typedef __attribute__((ext_vector_type(8))) short short8;
typedef __attribute__((ext_vector_type(4))) float f32x4;

__device__ __forceinline__ unsigned short f2bf(float f) {
  unsigned int u = __float_as_uint(f);
  u += 0x7FFF + ((u >> 16) & 1);          // round-to-nearest-even
  return (unsigned short)(u >> 16);
}

// async global->LDS, 16B per lane, wave-uniform LDS base + lane*16 (m97 recipe)
#define GLOAD_LDS16(gptr, lptr) \
  __builtin_amdgcn_global_load_lds((const __attribute__((address_space(1))) void*)(gptr), \
                                   (__attribute__((address_space(3))) void*)(lptr), 16, 0, 0)

// ---------------- cast W (3072x1024 f32) -> bf16 ----------------
__global__ void cast_w_kernel(const float* __restrict__ w, unsigned short* __restrict__ wb) {
  int i = blockIdx.x * blockDim.x + threadIdx.x;  // one float4 each
  const float4* w4 = (const float4*)w;
  float4 v = w4[i];
  unsigned int lo = (unsigned int)f2bf(v.x) | ((unsigned int)f2bf(v.y) << 16);
  unsigned int hi = (unsigned int)f2bf(v.z) | ((unsigned int)f2bf(v.w) << 16);
  ((uint2*)wb)[i] = make_uint2(lo, hi);
}

// ---------------- RMSNorm + cast to bf16 ----------------
__global__ void rmsnorm_kernel(const float* __restrict__ x, const float* __restrict__ gamma,
                               unsigned short* __restrict__ xn) {
  int row = blockIdx.x;
  int tid = threadIdx.x;
  const float4* x4 = (const float4*)(x + (size_t)row * DIMD);
  float4 v = x4[tid];
  float ss = v.x*v.x + v.y*v.y + v.z*v.z + v.w*v.w;
  #pragma unroll
  for (int m = 32; m >= 1; m >>= 1) ss += __shfl_xor(ss, m);
  __shared__ float red[4];
  if ((tid & 63) == 0) red[tid >> 6] = ss;
  __syncthreads();
  float tot = red[0] + red[1] + red[2] + red[3];
  float scale = 32.0f / fmaxf(sqrtf(tot), 1e-12f);   // sqrt(1024)=32
  const float4* g4 = (const float4*)gamma;
  float4 g = g4[tid];
  float a0 = v.x*scale*g.x, a1 = v.y*scale*g.y, a2 = v.z*scale*g.z, a3 = v.w*scale*g.w;
  unsigned int lo = (unsigned int)f2bf(a0) | ((unsigned int)f2bf(a1) << 16);
  unsigned int hi = (unsigned int)f2bf(a2) | ((unsigned int)f2bf(a3) << 16);
  ((uint2*)(xn + (size_t)row * DIMD))[tid] = make_uint2(lo, hi);
}

// ---------------- GEMM: C[M][E] = Xn[M][K] * W[E][K]^T, bf16 MFMA ----------------
// (unchanged from round 4 — 2-phase ceiling acknowledged; 8-phase rewrite is the
//  next isolated round)
#define BM 128
#define BN 128
#define BK 64

__global__ __launch_bounds__(256) void gemm_kernel(const unsigned short* __restrict__ A,
                                                   const unsigned short* __restrict__ Bw,
                                                   float* __restrict__ C) {
  __shared__ unsigned short Al[BM][BK];   // 16 KiB
  __shared__ unsigned short Bl[BN][BK];   // 16 KiB
  int tid = threadIdx.x;
  int l = tid & 63;
  int w = tid >> 6;
  int wr = w >> 1, wc = w & 1;
  int m0 = blockIdx.y * BM;
  int n0 = blockIdx.x * BN;
  int lrow = l & 15, lk = l >> 4;

  int srow_base = w * 32 + (l >> 3);
  int scol = (((l & 7) ^ (l >> 3)) * 8);   // inverse-swizzled source chunk (elements)

  f32x4 acc[4][4];
  #pragma unroll
  for (int i = 0; i < 4; i++)
    #pragma unroll
    for (int j = 0; j < 4; j++) acc[i][j] = (f32x4)(0.f);

  for (int k0 = 0; k0 < KK; k0 += BK) {
    __syncthreads();   // previous iter's LDS reads done before overwrite
    #pragma unroll
    for (int t = 0; t < 4; t++) {
      int row = srow_base + t * 8;
      GLOAD_LDS16(A  + (size_t)(m0 + row) * KK + k0 + scol, &Al[w*32 + t*8][0]);
      GLOAD_LDS16(Bw + (size_t)(n0 + row) * KK + k0 + scol, &Bl[w*32 + t*8][0]);
    }
    __syncthreads();   // drains vmcnt(0): tiles resident
    #pragma unroll
    for (int s = 0; s < 2; s++) {
      short8 af[4], bf[4];
      #pragma unroll
      for (int i = 0; i < 4; i++) {
        int r = wr*64 + i*16 + lrow;
        af[i] = *(const short8*)&Al[r][((s*4 + lk) ^ (r & 7)) * 8];
      }
      #pragma unroll
      for (int j = 0; j < 4; j++) {
        int r = wc*64 + j*16 + lrow;
        bf[j] = *(const short8*)&Bl[r][((s*4 + lk) ^ (r & 7)) * 8];
      }
      #pragma unroll
      for (int i = 0; i < 4; i++)
        #pragma unroll
        for (int j = 0; j < 4; j++)
          acc[i][j] = __builtin_amdgcn_mfma_f32_16x16x32_bf16(af[i], bf[j], acc[i][j], 0, 0, 0);
    }
  }

  // epilogue: C/D layout col = lane&15, row = (lane>>4)*4 + r  [m89-verified]
  #pragma unroll
  for (int i = 0; i < 4; i++) {
    int rowb = m0 + wr*64 + i*16 + lk*4;
    #pragma unroll
    for (int j = 0; j < 4; j++) {
      int col = n0 + wc*64 + j*16 + lrow;
      f32x4 v = acc[i][j];
      bool isg = (col >= 2*DIMD);
      #pragma unroll
      for (int r = 0; r < 4; r++) {
        float val = v[r];
        if (isg) val = 1.0f / (1.0f + __expf(-val));
        C[(size_t)(rowb + r)*EE + col] = val;
      }
    }
  }
}

// ---------------- chunked scan over n ----------------
// Round-5 fix: float4 (16B/lane) loads, CHUNK=32 so 256 blocks stay resident,
// batch-4 rows -> 8-12 outstanding 16B loads per thread. All unrolled (rule #20).
#define CHUNK 32
#define NCH (NN / CHUNK)   // 128

// pass 1: per-chunk aggregates. grid (NCH, BB), 256 thr; thread owns 4 channels.
__global__ void scan1_kernel(const float* __restrict__ qkva,
                             float* __restrict__ Aagg, float* __restrict__ Kagg) {
  int d = threadIdx.x * 4;
  int c = blockIdx.x;
  int b = blockIdx.y;
  const float* p = qkva + ((size_t)(b*NN + c*CHUNK)) * EE;
  float4 Aa = make_float4(1.f,1.f,1.f,1.f);
  float4 Kv = make_float4(0.f,0.f,0.f,0.f);
  for (int i0 = 0; i0 < CHUNK; i0 += 4) {
    float4 av[4], kvv[4];
    #pragma unroll
    for (int u = 0; u < 4; u++) av[u]  = *(const float4*)&p[(size_t)(i0+u)*EE + 2*DIMD + d];
    #pragma unroll
    for (int u = 0; u < 4; u++) kvv[u] = *(const float4*)&p[(size_t)(i0+u)*EE + DIMD + d];
    #pragma unroll
    for (int u = 0; u < 4; u++) {
      Kv.x = fmaf(av[u].x, Kv.x, kvv[u].x); Aa.x *= av[u].x;
      Kv.y = fmaf(av[u].y, Kv.y, kvv[u].y); Aa.y *= av[u].y;
      Kv.z = fmaf(av[u].z, Kv.z, kvv[u].z); Aa.z *= av[u].z;
      Kv.w = fmaf(av[u].w, Kv.w, kvv[u].w); Aa.w *= av[u].w;
    }
  }
  size_t idx = (size_t)(b*NCH + c)*DIMD + d;
  *(float4*)&Aagg[idx] = Aa;
  *(float4*)&Kagg[idx] = Kv;
}

// pass 2: exclusive prefix over chunks (per b,d channel; 2048 threads, scalar)
__global__ void scan2_kernel(const float* __restrict__ Aagg, const float* __restrict__ Kagg,
                             float* __restrict__ carry) {
  int t = blockIdx.x * 256 + threadIdx.x;   // 0..2047
  int b = t >> 10, d = t & (DIMD - 1);
  float cy = 0.f;
  for (int c0 = 0; c0 < NCH; c0 += 8) {
    float Av[8], Kv[8];
    #pragma unroll
    for (int u = 0; u < 8; u++) {
      size_t idx = (size_t)(b*NCH + c0 + u)*DIMD + d;
      Av[u] = Aagg[idx]; Kv[u] = Kagg[idx];
    }
    #pragma unroll
    for (int u = 0; u < 8; u++) {
      carry[(size_t)(b*NCH + c0 + u)*DIMD + d] = cy;
      cy = fmaf(Av[u], cy, Kv[u]);
    }
  }
}

// pass 3: re-scan each chunk with its carry, write out = q * kv_scan
__global__ void scan3_kernel(const float* __restrict__ qkva, const float* __restrict__ carry,
                             float* __restrict__ out) {
  int d = threadIdx.x * 4;
  int c = blockIdx.x;
  int b = blockIdx.y;
  const float* p = qkva + ((size_t)(b*NN + c*CHUNK)) * EE;
  float* o = out + ((size_t)(b*NN + c*CHUNK)) * DIMD;
  float4 Kv = *(const float4*)&carry[(size_t)(b*NCH + c)*DIMD + d];
  for (int i0 = 0; i0 < CHUNK; i0 += 4) {
    float4 av[4], kvv[4], qv[4];
    #pragma unroll
    for (int u = 0; u < 4; u++) av[u]  = *(const float4*)&p[(size_t)(i0+u)*EE + 2*DIMD + d];
    #pragma unroll
    for (int u = 0; u < 4; u++) kvv[u] = *(const float4*)&p[(size_t)(i0+u)*EE + DIMD + d];
    #pragma unroll
    for (int u = 0; u < 4; u++) qv[u]  = *(const float4*)&p[(size_t)(i0+u)*EE + d];
    #pragma unroll
    for (int u = 0; u < 4; u++) {
      float4 r;
      Kv.x = fmaf(av[u].x, Kv.x, kvv[u].x); r.x = qv[u].x * Kv.x;
      Kv.y = fmaf(av[u].y, Kv.y, kvv[u].y); r.y = qv[u].y * Kv.y;
      Kv.z = fmaf(av[u].z, Kv.z, kvv[u].z); r.z = qv[u].z * Kv.z;
      Kv.w = fmaf(av[u].w, Kv.w, kvv[u].w); r.w = qv[u].w * Kv.w;
      *(float4*)&o[(size_t)(i0+u)*DIMD + d] = r;
    }
  }
}

// ---------------- launch ----------------
// ws layout (bytes):
//   [0, 6 MiB)            W bf16        3072*1024*2   = 6,291,456
//   [6 MiB, 22 MiB)       Xn bf16       8192*1024*2   = 16,777,216
//   [22 MiB, 118 MiB)     qkva f32      8192*3072*4   = 100,663,296
//   Aagg / Kagg / carry   f32           2*128*1024*4  = 1,048,576 each
extern "C" void kernel_launch(void* const* d_in, const int* in_sizes, int n_in,
                              void* d_out, int out_size, void* d_ws, size_t ws_size,
                              hipStream_t stream) {
  const float* x     = (const float*)d_in[0];
  const float* gamma = (const float*)d_in[1];
  const float* wq    = (const float*)d_in[2];
  float* out = (float*)d_out;
  char* ws = (char*)d_ws;

  unsigned short* Wb = (unsigned short*)ws;
  unsigned short* Xn = (unsigned short*)(ws + 6291456);
  float* qkva        = (float*)(ws + 23068672);
  float* Aagg        = (float*)(ws + 123731968);
  float* Kagg        = (float*)(ws + 124780544);
  float* carry       = (float*)(ws + 125829120);

  cast_w_kernel<<<(EE*KK)/(256*4), 256, 0, stream>>>(wq, Wb);
  rmsnorm_kernel<<<MM, 256, 0, stream>>>(x, gamma, Xn);
  gemm_kernel<<<dim3(EE/BN, MM/BM), 256, 0, stream>>>(Xn, Wb, qkva);
  scan1_kernel<<<dim3(NCH, BB), 256, 0, stream>>>(qkva, Aagg, Kagg);
  scan2_kernel<<<dim3((BB*DIMD)/256), 256, 0, stream>>>(Aagg, Kagg, carry);
  scan3_kernel<<<dim3(NCH, BB), 256, 0, stream>>>(qkva, carry, out);
}

// Round 8
// 201.451 us; speedup vs baseline: 1.1164x; 1.0148x over previous
//
#include <hip/hip_runtime.h>
#include <cstdint>
#include <cstddef>

// Problem constants (fixed by reference setup_inputs)
#define DIMD 1024
#define BB 2
#define NN 4096
#define MM (BB*NN)      // 8192 rows
#define EE (3*DIMD)     // 3072 output cols
#define KK DIMD         // 1024

typedef __attribute__((ext_vector_type(8))) short short8;
typedef __attribute__((ext_vector_type(4))) float f32x4;

__device__ __forceinline__ unsigned short f2bf(float f) {
  unsigned int u = __float_as_uint(f);
  u += 0x7FFF + ((u >> 16) & 1);          // round-to-nearest-even
  return (unsigned short)(u >> 16);
}

// async global->LDS, 16B per lane, wave-uniform LDS base + lane*16 (m97 recipe)
#define GLOAD_LDS16(gptr, lptr) \
  __builtin_amdgcn_global_load_lds((const __attribute__((address_space(1))) void*)(gptr), \
                                   (__attribute__((address_space(3))) void*)(lptr), 16, 0, 0)

// ---------------- cast W (3072x1024 f32) -> bf16 ----------------
__global__ void cast_w_kernel(const float* __restrict__ w, unsigned short* __restrict__ wb) {
  int i = blockIdx.x * blockDim.x + threadIdx.x;  // one float4 each
  const float4* w4 = (const float4*)w;
  float4 v = w4[i];
  unsigned int lo = (unsigned int)f2bf(v.x) | ((unsigned int)f2bf(v.y) << 16);
  unsigned int hi = (unsigned int)f2bf(v.z) | ((unsigned int)f2bf(v.w) << 16);
  ((uint2*)wb)[i] = make_uint2(lo, hi);
}

// ---------------- RMSNorm + cast to bf16 ----------------
__global__ void rmsnorm_kernel(const float* __restrict__ x, const float* __restrict__ gamma,
                               unsigned short* __restrict__ xn) {
  int row = blockIdx.x;
  int tid = threadIdx.x;
  const float4* x4 = (const float4*)(x + (size_t)row * DIMD);
  float4 v = x4[tid];
  float ss = v.x*v.x + v.y*v.y + v.z*v.z + v.w*v.w;
  #pragma unroll
  for (int m = 32; m >= 1; m >>= 1) ss += __shfl_xor(ss, m);
  __shared__ float red[4];
  if ((tid & 63) == 0) red[tid >> 6] = ss;
  __syncthreads();
  float tot = red[0] + red[1] + red[2] + red[3];
  float scale = 32.0f / fmaxf(sqrtf(tot), 1e-12f);   // sqrt(1024)=32
  const float4* g4 = (const float4*)gamma;
  float4 g = g4[tid];
  float a0 = v.x*scale*g.x, a1 = v.y*scale*g.y, a2 = v.z*scale*g.z, a3 = v.w*scale*g.w;
  unsigned int lo = (unsigned int)f2bf(a0) | ((unsigned int)f2bf(a1) << 16);
  unsigned int hi = (unsigned int)f2bf(a2) | ((unsigned int)f2bf(a3) << 16);
  ((uint2*)(xn + (size_t)row * DIMD))[tid] = make_uint2(lo, hi);
}

// ---------------- GEMM: bf16 MFMA, 128x128 tile, DOUBLE-BUFFERED ----------------
// Round-8: T3-minimum pipeline. Per K-step: issue next tile's global_load_lds
// FIRST, then ds_read+MFMA current tile, then ONE __syncthreads() (implicit
// vmcnt(0)+lgkmcnt(0) drain lands after the compute window, not before it).
// Sync proof: barrier at end of step t guarantees all reads of buf[t&1]
// completed (MFMA consumed them under lgkmcnt) before step t+1 overwrites it.
// Epilogue writes SoA planes q/kv/a (sigmoid applied to a). Fragment layout,
// XOR swizzle, staging geometry inherited unchanged from verified round-7.
#define BM 128
#define BN 128
#define BK 64
#define NT (KK/BK)   // 16 K-steps

__global__ __launch_bounds__(256) void gemm_kernel(const unsigned short* __restrict__ A,
                                                   const unsigned short* __restrict__ Bw,
                                                   float* __restrict__ q_pl,
                                                   float* __restrict__ kv_pl,
                                                   float* __restrict__ a_pl) {
  __shared__ unsigned short Al[2][BM][BK];   // 32 KiB
  __shared__ unsigned short Bl[2][BN][BK];   // 32 KiB
  int tid = threadIdx.x;
  int l = tid & 63;
  int w = tid >> 6;
  int wr = w >> 1, wc = w & 1;
  int m0 = blockIdx.y * BM;
  int n0 = blockIdx.x * BN;
  int lrow = l & 15, lk = l >> 4;

  // staging geometry (verified): wave w rows [w*32, w*32+32); lane l writes LDS
  // row w*32+t*8+(l>>3), chunk slot (l&7); source chunk inverse-swizzled.
  int srow = w * 32 + (l >> 3);
  int scol = (((l & 7) ^ (l >> 3)) * 8);
  const unsigned short* Ag = A  + (size_t)(m0 + srow) * KK + scol;
  const unsigned short* Bg = Bw + (size_t)(n0 + srow) * KK + scol;

  f32x4 acc[4][4];
  #pragma unroll
  for (int i = 0; i < 4; i++)
    #pragma unroll
    for (int j = 0; j < 4; j++) acc[i][j] = (f32x4)(0.f);

  // prologue: stage tile 0 into buf 0
  #pragma unroll
  for (int t = 0; t < 4; t++) {
    GLOAD_LDS16(Ag + (size_t)(t*8) * KK, &Al[0][w*32 + t*8][0]);
    GLOAD_LDS16(Bg + (size_t)(t*8) * KK, &Bl[0][w*32 + t*8][0]);
  }
  __syncthreads();

  int cur = 0;
  for (int kt = 0; kt < NT; ++kt) {
    // issue next tile's loads BEFORE compute (overlap window = ds_read+MFMA)
    if (kt + 1 < NT) {
      int nk = (kt + 1) * BK;
      #pragma unroll
      for (int t = 0; t < 4; t++) {
        GLOAD_LDS16(Ag + (size_t)(t*8) * KK + nk, &Al[cur ^ 1][w*32 + t*8][0]);
        GLOAD_LDS16(Bg + (size_t)(t*8) * KK + nk, &Bl[cur ^ 1][w*32 + t*8][0]);
      }
    }
    // compute current tile
    #pragma unroll
    for (int s = 0; s < 2; s++) {
      short8 af[4], bf[4];
      #pragma unroll
      for (int i = 0; i < 4; i++) {
        int r = wr*64 + i*16 + lrow;
        af[i] = *(const short8*)&Al[cur][r][((s*4 + lk) ^ (r & 7)) * 8];
      }
      #pragma unroll
      for (int j = 0; j < 4; j++) {
        int r = wc*64 + j*16 + lrow;
        bf[j] = *(const short8*)&Bl[cur][r][((s*4 + lk) ^ (r & 7)) * 8];
      }
      #pragma unroll
      for (int i = 0; i < 4; i++)
        #pragma unroll
        for (int j = 0; j < 4; j++)
          acc[i][j] = __builtin_amdgcn_mfma_f32_16x16x32_bf16(af[i], bf[j], acc[i][j], 0, 0, 0);
    }
    if (kt + 1 < NT) {
      __syncthreads();   // drains stage loads + fences buffer swap
      cur ^= 1;
    }
  }

  // epilogue: C/D layout col = lane&15, row = (lane>>4)*4 + r  [m89-verified]
  // SoA planes: block's col range [n0, n0+128) lies in exactly one plane.
  int plane = n0 >> 10;
  float* P = (plane == 0) ? q_pl : ((plane == 1) ? kv_pl : a_pl);
  bool isg = (plane == 2);
  int pn0 = n0 & 1023;
  #pragma unroll
  for (int i = 0; i < 4; i++) {
    int rowb = m0 + wr*64 + i*16 + lk*4;
    #pragma unroll
    for (int j = 0; j < 4; j++) {
      int pcol = pn0 + wc*64 + j*16 + lrow;
      f32x4 v = acc[i][j];
      #pragma unroll
      for (int r = 0; r < 4; r++) {
        float val = v[r];
        if (isg) val = 1.0f / (1.0f + __expf(-val));
        P[(size_t)(rowb + r)*DIMD + pcol] = val;
      }
    }
  }
}

// ---------------- chunked scan over n (SoA planes) ----------------
#define CHUNK 32
#define NCH (NN / CHUNK)   // 128

// pass 1: per-chunk aggregates. grid (NCH, BB), 256 thr; thread owns 4 channels.
__global__ void scan1_kernel(const float* __restrict__ kv_pl, const float* __restrict__ a_pl,
                             float* __restrict__ Aagg, float* __restrict__ Kagg) {
  int d = threadIdx.x * 4;
  int c = blockIdx.x;
  int b = blockIdx.y;
  size_t base = ((size_t)(b*NN + c*CHUNK)) * DIMD + d;
  const float* pa = a_pl + base;
  const float* pk = kv_pl + base;
  float4 Aa = make_float4(1.f,1.f,1.f,1.f);
  float4 Kv = make_float4(0.f,0.f,0.f,0.f);
  for (int i0 = 0; i0 < CHUNK; i0 += 4) {
    float4 av[4], kvv[4];
    #pragma unroll
    for (int u = 0; u < 4; u++) av[u]  = *(const float4*)&pa[(size_t)(i0+u)*DIMD];
    #pragma unroll
    for (int u = 0; u < 4; u++) kvv[u] = *(const float4*)&pk[(size_t)(i0+u)*DIMD];
    #pragma unroll
    for (int u = 0; u < 4; u++) {
      Kv.x = fmaf(av[u].x, Kv.x, kvv[u].x); Aa.x *= av[u].x;
      Kv.y = fmaf(av[u].y, Kv.y, kvv[u].y); Aa.y *= av[u].y;
      Kv.z = fmaf(av[u].z, Kv.z, kvv[u].z); Aa.z *= av[u].z;
      Kv.w = fmaf(av[u].w, Kv.w, kvv[u].w); Aa.w *= av[u].w;
    }
  }
  size_t idx = (size_t)(b*NCH + c)*DIMD + d;
  *(float4*)&Aagg[idx] = Aa;
  *(float4*)&Kagg[idx] = Kv;
}

// pass 2: exclusive prefix over chunks (per b,d channel; 2048 threads)
__global__ void scan2_kernel(const float* __restrict__ Aagg, const float* __restrict__ Kagg,
                             float* __restrict__ carry) {
  int t = blockIdx.x * 256 + threadIdx.x;   // 0..2047
  int b = t >> 10, d = t & (DIMD - 1);
  float cy = 0.f;
  for (int c0 = 0; c0 < NCH; c0 += 8) {
    float Av[8], Kv[8];
    #pragma unroll
    for (int u = 0; u < 8; u++) {
      size_t idx = (size_t)(b*NCH + c0 + u)*DIMD + d;
      Av[u] = Aagg[idx]; Kv[u] = Kagg[idx];
    }
    #pragma unroll
    for (int u = 0; u < 8; u++) {
      carry[(size_t)(b*NCH + c0 + u)*DIMD + d] = cy;
      cy = fmaf(Av[u], cy, Kv[u]);
    }
  }
}

// pass 3: re-scan each chunk with its carry, write out = q * kv_scan
__global__ void scan3_kernel(const float* __restrict__ q_pl, const float* __restrict__ kv_pl,
                             const float* __restrict__ a_pl, const float* __restrict__ carry,
                             float* __restrict__ out) {
  int d = threadIdx.x * 4;
  int c = blockIdx.x;
  int b = blockIdx.y;
  size_t base = ((size_t)(b*NN + c*CHUNK)) * DIMD + d;
  const float* pa = a_pl + base;
  const float* pk = kv_pl + base;
  const float* pq = q_pl + base;
  float* o = out + base;
  float4 Kv = *(const float4*)&carry[(size_t)(b*NCH + c)*DIMD + d];
  for (int i0 = 0; i0 < CHUNK; i0 += 4) {
    float4 av[4], kvv[4], qv[4];
    #pragma unroll
    for (int u = 0; u < 4; u++) av[u]  = *(const float4*)&pa[(size_t)(i0+u)*DIMD];
    #pragma unroll
    for (int u = 0; u < 4; u++) kvv[u] = *(const float4*)&pk[(size_t)(i0+u)*DIMD];
    #pragma unroll
    for (int u = 0; u < 4; u++) qv[u]  = *(const float4*)&pq[(size_t)(i0+u)*DIMD];
    #pragma unroll
    for (int u = 0; u < 4; u++) {
      float4 r;
      Kv.x = fmaf(av[u].x, Kv.x, kvv[u].x); r.x = qv[u].x * Kv.x;
      Kv.y = fmaf(av[u].y, Kv.y, kvv[u].y); r.y = qv[u].y * Kv.y;
      Kv.z = fmaf(av[u].z, Kv.z, kvv[u].z); r.z = qv[u].z * Kv.z;
      Kv.w = fmaf(av[u].w, Kv.w, kvv[u].w); r.w = qv[u].w * Kv.w;
      *(float4*)&o[(size_t)(i0+u)*DIMD] = r;
    }
  }
}

// ---------------- launch ----------------
// ws layout (bytes):
//   [0, 6 MiB)            W bf16        3072*1024*2   = 6,291,456
//   [6 MiB, 22 MiB)       Xn bf16       8192*1024*2   = 16,777,216
//   q_plane  f32  8192*1024*4 = 33,554,432  @ 23,068,672
//   kv_plane f32  33,554,432               @ 56,623,104
//   a_plane  f32  33,554,432               @ 90,177,536
//   Aagg / Kagg / carry  f32  1 MiB each   @ 123,731,968.. (same cap as round 7)
extern "C" void kernel_launch(void* const* d_in, const int* in_sizes, int n_in,
                              void* d_out, int out_size, void* d_ws, size_t ws_size,
                              hipStream_t stream) {
  const float* x     = (const float*)d_in[0];
  const float* gamma = (const float*)d_in[1];
  const float* wq    = (const float*)d_in[2];
  float* out = (float*)d_out;
  char* ws = (char*)d_ws;

  unsigned short* Wb = (unsigned short*)ws;
  unsigned short* Xn = (unsigned short*)(ws + 6291456);
  float* q_pl        = (float*)(ws + 23068672);
  float* kv_pl       = (float*)(ws + 56623104);
  float* a_pl        = (float*)(ws + 90177536);
  float* Aagg        = (float*)(ws + 123731968);
  float* Kagg        = (float*)(ws + 124780544);
  float* carry       = (float*)(ws + 125829120);

  cast_w_kernel<<<(EE*KK)/(256*4), 256, 0, stream>>>(wq, Wb);
  rmsnorm_kernel<<<MM, 256, 0, stream>>>(x, gamma, Xn);
  gemm_kernel<<<dim3(EE/BN, MM/BM), 256, 0, stream>>>(Xn, Wb, q_pl, kv_pl, a_pl);
  scan1_kernel<<<dim3(NCH, BB), 256, 0, stream>>>(kv_pl, a_pl, Aagg, Kagg);
  scan2_kernel<<<dim3((BB*DIMD)/256), 256, 0, stream>>>(Aagg, Kagg, carry);
  scan3_kernel<<<dim3(NCH, BB), 256, 0, stream>>>(q_pl, kv_pl, a_pl, carry, out);
}

// Round 12
// 198.807 us; speedup vs baseline: 1.1313x; 1.0133x over previous
//
#include <hip/hip_runtime.h>
#include <cstdint>
#include <cstddef>

// Problem constants (fixed by reference setup_inputs)
#define DIMD 1024
#define BB 2
#define NN 4096
#define MM (BB*NN)      // 8192 rows
#define EE (3*DIMD)     // 3072 output cols
#define KK DIMD         // 1024

typedef __attribute__((ext_vector_type(8))) short short8;
typedef __attribute__((ext_vector_type(4))) float f32x4;

__device__ __forceinline__ unsigned short f2bf(float f) {
  unsigned int u = __float_as_uint(f);
  u += 0x7FFF + ((u >> 16) & 1);          // round-to-nearest-even
  return (unsigned short)(u >> 16);
}
__device__ __forceinline__ float bf2f(unsigned short h) {
  return __uint_as_float((unsigned int)h << 16);
}

// async global->LDS, 16B per lane, wave-uniform LDS base + lane*16 (m97 recipe)
#define GLOAD_LDS16(gptr, lptr) \
  __builtin_amdgcn_global_load_lds((const __attribute__((address_space(1))) void*)(gptr), \
                                   (__attribute__((address_space(3))) void*)(lptr), 16, 0, 0)

// ---------------- cast W (3072x1024 f32) -> bf16 ----------------
__global__ void cast_w_kernel(const float* __restrict__ w, unsigned short* __restrict__ wb) {
  int i = blockIdx.x * blockDim.x + threadIdx.x;  // one float4 each
  const float4* w4 = (const float4*)w;
  float4 v = w4[i];
  unsigned int lo = (unsigned int)f2bf(v.x) | ((unsigned int)f2bf(v.y) << 16);
  unsigned int hi = (unsigned int)f2bf(v.z) | ((unsigned int)f2bf(v.w) << 16);
  ((uint2*)wb)[i] = make_uint2(lo, hi);
}

// ---------------- RMSNorm + cast to bf16 ----------------
__global__ void rmsnorm_kernel(const float* __restrict__ x, const float* __restrict__ gamma,
                               unsigned short* __restrict__ xn) {
  int row = blockIdx.x;
  int tid = threadIdx.x;
  const float4* x4 = (const float4*)(x + (size_t)row * DIMD);
  float4 v = x4[tid];
  float ss = v.x*v.x + v.y*v.y + v.z*v.z + v.w*v.w;
  #pragma unroll
  for (int m = 32; m >= 1; m >>= 1) ss += __shfl_xor(ss, m);
  __shared__ float red[4];
  if ((tid & 63) == 0) red[tid >> 6] = ss;
  __syncthreads();
  float tot = red[0] + red[1] + red[2] + red[3];
  float scale = 32.0f / fmaxf(sqrtf(tot), 1e-12f);   // sqrt(1024)=32
  const float4* g4 = (const float4*)gamma;
  float4 g = g4[tid];
  float a0 = v.x*scale*g.x, a1 = v.y*scale*g.y, a2 = v.z*scale*g.z, a3 = v.w*scale*g.w;
  unsigned int lo = (unsigned int)f2bf(a0) | ((unsigned int)f2bf(a1) << 16);
  unsigned int hi = (unsigned int)f2bf(a2) | ((unsigned int)f2bf(a3) << 16);
  ((uint2*)(xn + (size_t)row * DIMD))[tid] = make_uint2(lo, hi);
}

// ---------------- GEMM: bf16 MFMA, 128x128 tile, double-buffered ----------------
// Round-9: + XCD-bijective block swizzle (nwg=1536, 1536%8==0 -> (lin&7)*192+lin>>3);
//          kv/a planes written as bf16 (q stays f32). Core loop unchanged from
//          verified round-8.
#define BM 128
#define BN 128
#define BK 64
#define NT (KK/BK)   // 16 K-steps
#define NWGX 24      // EE/BN
#define NWGY 64      // MM/BM

__global__ __launch_bounds__(256) void gemm_kernel(const unsigned short* __restrict__ A,
                                                   const unsigned short* __restrict__ Bw,
                                                   float* __restrict__ q_pl,
                                                   unsigned short* __restrict__ kv_pl,
                                                   unsigned short* __restrict__ a_pl) {
  __shared__ unsigned short Al[2][BM][BK];   // 32 KiB
  __shared__ unsigned short Bl[2][BN][BK];   // 32 KiB
  int tid = threadIdx.x;
  int l = tid & 63;
  int w = tid >> 6;
  int wr = w >> 1, wc = w & 1;

  // XCD-aware bijective swizzle: 1536 blocks = 8 XCDs x 192
  int lin = blockIdx.y * NWGX + blockIdx.x;
  int swz = (lin & 7) * (NWGX * NWGY / 8) + (lin >> 3);
  int n0 = (swz % NWGX) * BN;
  int m0 = (swz / NWGX) * BM;
  int lrow = l & 15, lk = l >> 4;

  // staging geometry (verified): wave w rows [w*32, w*32+32); lane l writes LDS
  // row w*32+t*8+(l>>3), chunk slot (l&7); source chunk inverse-swizzled.
  int srow = w * 32 + (l >> 3);
  int scol = (((l & 7) ^ (l >> 3)) * 8);
  const unsigned short* Ag = A  + (size_t)(m0 + srow) * KK + scol;
  const unsigned short* Bg = Bw + (size_t)(n0 + srow) * KK + scol;

  f32x4 acc[4][4];
  #pragma unroll
  for (int i = 0; i < 4; i++)
    #pragma unroll
    for (int j = 0; j < 4; j++) acc[i][j] = (f32x4)(0.f);

  // prologue: stage tile 0 into buf 0
  #pragma unroll
  for (int t = 0; t < 4; t++) {
    GLOAD_LDS16(Ag + (size_t)(t*8) * KK, &Al[0][w*32 + t*8][0]);
    GLOAD_LDS16(Bg + (size_t)(t*8) * KK, &Bl[0][w*32 + t*8][0]);
  }
  __syncthreads();

  int cur = 0;
  for (int kt = 0; kt < NT; ++kt) {
    if (kt + 1 < NT) {
      int nk = (kt + 1) * BK;
      #pragma unroll
      for (int t = 0; t < 4; t++) {
        GLOAD_LDS16(Ag + (size_t)(t*8) * KK + nk, &Al[cur ^ 1][w*32 + t*8][0]);
        GLOAD_LDS16(Bg + (size_t)(t*8) * KK + nk, &Bl[cur ^ 1][w*32 + t*8][0]);
      }
    }
    #pragma unroll
    for (int s = 0; s < 2; s++) {
      short8 af[4], bf[4];
      #pragma unroll
      for (int i = 0; i < 4; i++) {
        int r = wr*64 + i*16 + lrow;
        af[i] = *(const short8*)&Al[cur][r][((s*4 + lk) ^ (r & 7)) * 8];
      }
      #pragma unroll
      for (int j = 0; j < 4; j++) {
        int r = wc*64 + j*16 + lrow;
        bf[j] = *(const short8*)&Bl[cur][r][((s*4 + lk) ^ (r & 7)) * 8];
      }
      #pragma unroll
      for (int i = 0; i < 4; i++)
        #pragma unroll
        for (int j = 0; j < 4; j++)
          acc[i][j] = __builtin_amdgcn_mfma_f32_16x16x32_bf16(af[i], bf[j], acc[i][j], 0, 0, 0);
    }
    if (kt + 1 < NT) {
      __syncthreads();
      cur ^= 1;
    }
  }

  // epilogue: C/D layout col = lane&15, row = (lane>>4)*4 + r  [m89-verified]
  // plane 0 (q): f32.  plane 1 (kv): bf16.  plane 2 (a): sigmoid -> bf16.
  int plane = n0 >> 10;
  int pn0 = n0 & 1023;
  #pragma unroll
  for (int i = 0; i < 4; i++) {
    int rowb = m0 + wr*64 + i*16 + lk*4;
    #pragma unroll
    for (int j = 0; j < 4; j++) {
      int pcol = pn0 + wc*64 + j*16 + lrow;
      f32x4 v = acc[i][j];
      #pragma unroll
      for (int r = 0; r < 4; r++) {
        float val = v[r];
        size_t idx = (size_t)(rowb + r)*DIMD + pcol;
        if (plane == 0) {
          q_pl[idx] = val;
        } else if (plane == 1) {
          kv_pl[idx] = f2bf(val);
        } else {
          a_pl[idx] = f2bf(1.0f / (1.0f + __expf(-val)));
        }
      }
    }
  }
}

// ---------------- chunked scan over n (SoA planes; kv/a bf16) ----------------
#define CHUNK 32
#define NCH (NN / CHUNK)   // 128

// pass 1: per-chunk aggregates. grid (NCH, BB), 256 thr; thread owns 4 channels.
__global__ void scan1_kernel(const unsigned short* __restrict__ kv_pl,
                             const unsigned short* __restrict__ a_pl,
                             float* __restrict__ Aagg, float* __restrict__ Kagg) {
  int d = threadIdx.x * 4;
  int c = blockIdx.x;
  int b = blockIdx.y;
  size_t base = ((size_t)(b*NN + c*CHUNK)) * DIMD + d;
  const unsigned short* pa = a_pl + base;
  const unsigned short* pk = kv_pl + base;
  float4 Aa = make_float4(1.f,1.f,1.f,1.f);
  float4 Kv = make_float4(0.f,0.f,0.f,0.f);
  for (int i0 = 0; i0 < CHUNK; i0 += 4) {
    ushort4 au[4], ku[4];
    #pragma unroll
    for (int u = 0; u < 4; u++) au[u] = *(const ushort4*)&pa[(size_t)(i0+u)*DIMD];
    #pragma unroll
    for (int u = 0; u < 4; u++) ku[u] = *(const ushort4*)&pk[(size_t)(i0+u)*DIMD];
    #pragma unroll
    for (int u = 0; u < 4; u++) {
      float ax = bf2f(au[u].x), ay = bf2f(au[u].y), az = bf2f(au[u].z), aw = bf2f(au[u].w);
      Kv.x = fmaf(ax, Kv.x, bf2f(ku[u].x)); Aa.x *= ax;
      Kv.y = fmaf(ay, Kv.y, bf2f(ku[u].y)); Aa.y *= ay;
      Kv.z = fmaf(az, Kv.z, bf2f(ku[u].z)); Aa.z *= az;
      Kv.w = fmaf(aw, Kv.w, bf2f(ku[u].w)); Aa.w *= aw;
    }
  }
  size_t idx = (size_t)(b*NCH + c)*DIMD + d;
  *(float4*)&Aagg[idx] = Aa;
  *(float4*)&Kagg[idx] = Kv;
}

// pass 2: exclusive prefix over chunks (per b,d channel; 2048 threads)
__global__ void scan2_kernel(const float* __restrict__ Aagg, const float* __restrict__ Kagg,
                             float* __restrict__ carry) {
  int t = blockIdx.x * 256 + threadIdx.x;   // 0..2047
  int b = t >> 10, d = t & (DIMD - 1);
  float cy = 0.f;
  for (int c0 = 0; c0 < NCH; c0 += 8) {
    float Av[8], Kv[8];
    #pragma unroll
    for (int u = 0; u < 8; u++) {
      size_t idx = (size_t)(b*NCH + c0 + u)*DIMD + d;
      Av[u] = Aagg[idx]; Kv[u] = Kagg[idx];
    }
    #pragma unroll
    for (int u = 0; u < 8; u++) {
      carry[(size_t)(b*NCH + c0 + u)*DIMD + d] = cy;
      cy = fmaf(Av[u], cy, Kv[u]);
    }
  }
}

// pass 3: re-scan each chunk with its carry, write out = q * kv_scan
__global__ void scan3_kernel(const float* __restrict__ q_pl,
                             const unsigned short* __restrict__ kv_pl,
                             const unsigned short* __restrict__ a_pl,
                             const float* __restrict__ carry,
                             float* __restrict__ out) {
  int d = threadIdx.x * 4;
  int c = blockIdx.x;
  int b = blockIdx.y;
  size_t base = ((size_t)(b*NN + c*CHUNK)) * DIMD + d;
  const unsigned short* pa = a_pl + base;
  const unsigned short* pk = kv_pl + base;
  const float* pq = q_pl + base;
  float* o = out + base;
  float4 Kv = *(const float4*)&carry[(size_t)(b*NCH + c)*DIMD + d];
  for (int i0 = 0; i0 < CHUNK; i0 += 4) {
    ushort4 au[4], ku[4];
    float4 qv[4];
    #pragma unroll
    for (int u = 0; u < 4; u++) au[u] = *(const ushort4*)&pa[(size_t)(i0+u)*DIMD];
    #pragma unroll
    for (int u = 0; u < 4; u++) ku[u] = *(const ushort4*)&pk[(size_t)(i0+u)*DIMD];
    #pragma unroll
    for (int u = 0; u < 4; u++) qv[u] = *(const float4*)&pq[(size_t)(i0+u)*DIMD];
    #pragma unroll
    for (int u = 0; u < 4; u++) {
      float ax = bf2f(au[u].x), ay = bf2f(au[u].y), az = bf2f(au[u].z), aw = bf2f(au[u].w);
      float4 r;
      Kv.x = fmaf(ax, Kv.x, bf2f(ku[u].x)); r.x = qv[u].x * Kv.x;
      Kv.y = fmaf(ay, Kv.y, bf2f(ku[u].y)); r.y = qv[u].y * Kv.y;
      Kv.z = fmaf(az, Kv.z, bf2f(ku[u].z)); r.z = qv[u].z * Kv.z;
      Kv.w = fmaf(aw, Kv.w, bf2f(ku[u].w)); r.w = qv[u].w * Kv.w;
      *(float4*)&o[(size_t)(i0+u)*DIMD] = r;
    }
  }
}

// ---------------- launch ----------------
// ws layout (bytes):
//   Wb   bf16  6,291,456   @ 0
//   Xn   bf16 16,777,216   @ 6,291,456
//   q_pl f32  33,554,432   @ 23,068,672
//   kv_pl bf16 16,777,216  @ 56,623,104
//   a_pl  bf16 16,777,216  @ 73,400,320
//   Aagg f32   1,048,576   @ 90,177,536
//   Kagg f32   1,048,576   @ 91,226,112
//   carry f32  1,048,576   @ 92,274,688    (total ~93 MiB, < prior 126 MiB)
extern "C" void kernel_launch(void* const* d_in, const int* in_sizes, int n_in,
                              void* d_out, int out_size, void* d_ws, size_t ws_size,
                              hipStream_t stream) {
  const float* x     = (const float*)d_in[0];
  const float* gamma = (const float*)d_in[1];
  const float* wq    = (const float*)d_in[2];
  float* out = (float*)d_out;
  char* ws = (char*)d_ws;

  unsigned short* Wb   = (unsigned short*)ws;
  unsigned short* Xn   = (unsigned short*)(ws + 6291456);
  float* q_pl          = (float*)(ws + 23068672);
  unsigned short* kv_pl= (unsigned short*)(ws + 56623104);
  unsigned short* a_pl = (unsigned short*)(ws + 73400320);
  float* Aagg          = (float*)(ws + 90177536);
  float* Kagg          = (float*)(ws + 91226112);
  float* carry         = (float*)(ws + 92274688);

  cast_w_kernel<<<(EE*KK)/(256*4), 256, 0, stream>>>(wq, Wb);
  rmsnorm_kernel<<<MM, 256, 0, stream>>>(x, gamma, Xn);
  gemm_kernel<<<dim3(NWGX, NWGY), 256, 0, stream>>>(Xn, Wb, q_pl, kv_pl, a_pl);
  scan1_kernel<<<dim3(NCH, BB), 256, 0, stream>>>(kv_pl, a_pl, Aagg, Kagg);
  scan2_kernel<<<dim3((BB*DIMD)/256), 256, 0, stream>>>(Aagg, Kagg, carry);
  scan3_kernel<<<dim3(NCH, BB), 256, 0, stream>>>(q_pl, kv_pl, a_pl, carry, out);
}